// Round 5
// baseline (566.035 us; speedup 1.0000x reference)
//
#include <hip/hip_runtime.h>
#include <hip/hip_cooperative_groups.h>

namespace cg = cooperative_groups;

#define N_OBJ 1024
#define E_P   32768

typedef float f32x4 __attribute__((ext_vector_type(4)));
typedef short bf16x8 __attribute__((ext_vector_type(8)));
typedef unsigned short u16x4 __attribute__((ext_vector_type(4)));

__device__ __forceinline__ unsigned short f2bf(float f) {
    unsigned u = __float_as_uint(f);
    u = u + 0x7FFFu + ((u >> 16) & 1u);   // RNE
    return (unsigned short)(u >> 16);
}

// ---- copy split (float4 units): total = 1024*1024*64/4 = 16777216 ----
#define LEN_A   1048576
#define OFF_A   0
#define LEN_B   393216
#define OFF_B   (OFF_A + LEN_A)
#define LEN_C   1048576
#define OFF_C   (OFF_B + LEN_B)
#define LEN_C2  393216
#define OFF_C2  (OFF_C + LEN_C)
#define LEN_D   1310720
#define OFF_D   (OFF_C2 + LEN_C2)
#define LEN_E   12582912
#define OFF_E   (OFF_D + LEN_D)

struct Params {
    const float* feats; const float* bb; const int* pairs;
    const float* W1; const float* b1; const float* W2; const float* b2;
    float* out_feats; float* out_pairs;
    const float4* csrc; float4* cdst;
    unsigned short* featsb; unsigned short* w1pqT; unsigned short* w1cT; unsigned short* w2T;
    float* P; float* Q; float* HS;
    int* counts; int* cursor; int* csr_obj; unsigned* brec; int* bcnt;
};

__device__ __forceinline__ void copy_role(const float4* __restrict__ src,
                                          float4* __restrict__ dst,
                                          int off, int len, int nb, int cb) {
    int stride = nb * 256;
    int i = off + cb * 256 + threadIdx.x;
    int end = off + len;
    for (; i + stride < end; i += 2 * stride) {
        float4 a = src[i];
        float4 b = src[i + stride];
        dst[i] = a;
        dst[i + stride] = b;
    }
    if (i < end) dst[i] = src[i];
}

__global__ __launch_bounds__(256, 3) void k_fused(Params p) {
    cg::grid_group grid = cg::this_grid();
    const int G = gridDim.x, bid = blockIdx.x, tid = threadIdx.x;
    const int NC = G / 3;          // copy blocks in split phases
    const int GC = G - NC;         // compute blocks in split phases

    __shared__ float lds[32][33];
    __shared__ int buf[2][256];

    // ================= Phase A: weight transpose/convert + pairs/hist =================
    if (bid < GC) {
        for (int job = bid; job < 2112; job += GC) {
            if (job >= 1856) {                 // pairs passthrough + histogram
                int i = (job - 1856) * 256 + tid;
                p.out_pairs[i] = (float)p.pairs[i];
                if (i < E_P) atomicAdd(&p.counts[p.pairs[2 * i]], 1);
            } else if (job >= 1600) {          // featsb straight convert
                int base = (job - 1600) * 2048 + tid * 8;
                float4 v0 = *(const float4*)&p.feats[base];
                float4 v1 = *(const float4*)&p.feats[base + 4];
                u16x4 o0 = { f2bf(v0.x), f2bf(v0.y), f2bf(v0.z), f2bf(v0.w) };
                u16x4 o1 = { f2bf(v1.x), f2bf(v1.y), f2bf(v1.z), f2bf(v1.w) };
                *(u16x4*)&p.featsb[base] = o0;
                *(u16x4*)&p.featsb[base + 4] = o1;
            } else {                           // 32x32 transpose+convert via LDS
                const float* in; unsigned short* out;
                int LDI, LDO, r0, c0, nbase, kbase;
                if (job < 1024) {              // W1[0:1024] -> w1pqT [2048][512]
                    r0 = (job >> 5) * 32; c0 = (job & 31) * 32;
                    in = p.W1; LDI = 1024; out = p.w1pqT; LDO = 512;
                    nbase = c0 + (r0 >= 512 ? 1024 : 0); kbase = r0 & 511;
                } else if (job < 1088) {       // W1[1024:1088] -> w1cT [1024][64]
                    int t = job - 1024; r0 = 1024 + (t >> 5) * 32; c0 = (t & 31) * 32;
                    in = p.W1; LDI = 1024; out = p.w1cT; LDO = 64;
                    nbase = c0; kbase = r0 - 1024;
                } else {                       // W2 [1024][512] -> w2T [512][1024]
                    int t = job - 1088; r0 = (t >> 4) * 32; c0 = (t & 15) * 32;
                    in = p.W2; LDI = 512; out = p.w2T; LDO = 1024;
                    nbase = c0; kbase = r0;
                }
                __syncthreads();
                int ti = tid >> 3, tj = (tid & 7) * 4;
                float4 v = *(const float4*)&in[(size_t)(r0 + ti) * LDI + c0 + tj];
                lds[ti][tj] = v.x; lds[ti][tj + 1] = v.y; lds[ti][tj + 2] = v.z; lds[ti][tj + 3] = v.w;
                __syncthreads();
                int oc = tid >> 3, oj = (tid & 7) * 4;
                u16x4 o = { f2bf(lds[oj][oc]), f2bf(lds[oj + 1][oc]),
                            f2bf(lds[oj + 2][oc]), f2bf(lds[oj + 3][oc]) };
                *(u16x4*)&out[(size_t)(nbase + oc) * LDO + kbase + oj] = o;
            }
        }
    } else {
        copy_role(p.csrc, p.cdst, OFF_A, LEN_A, NC, bid - GC);
    }
    grid.sync();

    // ================= Phase B: scan (block 0) =================
    if (bid == 0) {
        int c[4]; int s = 0;
        #pragma unroll
        for (int i = 0; i < 4; ++i) { c[i] = p.counts[tid * 4 + i]; s += c[i]; }
        buf[0][tid] = s;
        __syncthreads();
        int sel = 0;
        for (int d = 1; d < 256; d <<= 1) {
            int v = buf[sel][tid];
            if (tid >= d) v += buf[sel][tid - d];
            buf[sel ^ 1][tid] = v;
            sel ^= 1;
            __syncthreads();
        }
        int base = buf[sel][tid] - s;   // exclusive prefix of pair counts
        int run = base;
        #pragma unroll
        for (int i = 0; i < 4; ++i) { p.cursor[tid * 4 + i] = run; run += c[i]; }
        // batch records
        int nb[4]; int t = 0;
        #pragma unroll
        for (int i = 0; i < 4; ++i) { nb[i] = (c[i] + 15) >> 4; t += nb[i]; }
        __syncthreads();
        buf[0][tid] = t;
        __syncthreads();
        sel = 0;
        for (int d = 1; d < 256; d <<= 1) {
            int v = buf[sel][tid];
            if (tid >= d) v += buf[sel][tid - d];
            buf[sel ^ 1][tid] = v;
            sel ^= 1;
            __syncthreads();
        }
        int bpos = buf[sel][tid] - t;
        int run2 = base;
        #pragma unroll
        for (int i = 0; i < 4; ++i) {
            int seg = tid * 4 + i;
            for (int k = 0; k < nb[i]; ++k) {
                int st = run2 + k * 16;
                int cnt = c[i] - k * 16; if (cnt > 16) cnt = 16;
                p.brec[bpos++] = (unsigned)st | ((unsigned)seg << 16) | ((unsigned)(cnt - 1) << 26);
            }
            run2 += c[i];
        }
        if (tid == 255) p.bcnt[0] = bpos;
    } else {
        copy_role(p.csrc, p.cdst, OFF_B, LEN_B, G - 1, bid - 1);
    }
    grid.sync();

    // ================= Phase C: scatter + PQ GEMM =================
    if (bid < GC) {
        for (int job = bid; job < 640; job += GC) {
            if (job < 128) {                   // scatter: csr_obj[pos] = obj
                int e = job * 256 + tid;
                int sidx = p.pairs[2 * e];
                int pos = atomicAdd(&p.cursor[sidx], 1);
                p.csr_obj[pos] = p.pairs[2 * e + 1];
            } else {                           // PQ GEMM tile
                int t = job - 128;
                int m0 = (t >> 5) * 64, n0 = (t & 31) * 64;
                int w = tid >> 6, l = tid & 63;
                int ln = l & 15, kb = (l >> 4) * 8;
                int row = m0 + w * 16 + ln;
                f32x4 acc[4] = {};
                for (int k0 = 0; k0 < 512; k0 += 32) {
                    bf16x8 a = *(const bf16x8*)&p.featsb[(size_t)row * 512 + k0 + kb];
                    #pragma unroll
                    for (int f = 0; f < 4; ++f) {
                        bf16x8 b = *(const bf16x8*)&p.w1pqT[(size_t)(n0 + f * 16 + ln) * 512 + k0 + kb];
                        acc[f] = __builtin_amdgcn_mfma_f32_16x16x32_bf16(a, b, acc[f], 0, 0, 0);
                    }
                }
                int mr = m0 + w * 16 + (l >> 4) * 4;
                if (n0 < 1024) {
                    #pragma unroll
                    for (int f = 0; f < 4; ++f) {
                        int n = n0 + f * 16 + ln;
                        float b1v = p.b1[n];
                        #pragma unroll
                        for (int r = 0; r < 4; ++r)
                            p.P[(size_t)(mr + r) * 1024 + n] = acc[f][r] + b1v;
                    }
                } else {
                    #pragma unroll
                    for (int f = 0; f < 4; ++f) {
                        int n = n0 - 1024 + f * 16 + ln;
                        #pragma unroll
                        for (int r = 0; r < 4; ++r)
                            p.Q[(size_t)(mr + r) * 1024 + n] = acc[f][r];
                    }
                }
            }
        }
    } else {
        copy_role(p.csrc, p.cdst, OFF_C, LEN_C, NC, bid - GC);
    }
    grid.sync();

    // ================= Phase C2: zero HS (aliases featsb/w1pqT, now dead) =================
    {
        float4 z = make_float4(0.f, 0.f, 0.f, 0.f);
        float4* hs4 = (float4*)p.HS;
        for (int i = bid * 256 + tid; i < 262144; i += G * 256) hs4[i] = z;
        copy_role(p.csrc, p.cdst, OFF_C2, LEN_C2, G, bid);
    }
    grid.sync();

    // ================= Phase D: segment batches =================
    if (bid < GC) {
        const int nbatch = p.bcnt[0];
        const int w = tid >> 6, l = tid & 63;
        const int ln = l & 15, g4 = l >> 4, kb = g4 * 8;
        const int n0 = w * 256;
        for (int j = bid; j < nbatch; j += GC) {
            unsigned rec = p.brec[j];
            int start = rec & 0xFFFF;
            int seg = (rec >> 16) & 0x3FF;
            int n = ((rec >> 26) & 15) + 1;

            int idx = start + (ln < n ? ln : n - 1);
            int obj = p.csr_obj[idx];
            const float* br = &p.bb[((size_t)seg * 1024 + (size_t)obj) * 64];
            float4 a0 = *(const float4*)&br[kb];
            float4 a1 = *(const float4*)&br[kb + 4];
            float4 a2 = *(const float4*)&br[32 + kb];
            float4 a3 = *(const float4*)&br[32 + kb + 4];
            bf16x8 A0, A1;
            A0[0] = (short)f2bf(a0.x); A0[1] = (short)f2bf(a0.y); A0[2] = (short)f2bf(a0.z); A0[3] = (short)f2bf(a0.w);
            A0[4] = (short)f2bf(a1.x); A0[5] = (short)f2bf(a1.y); A0[6] = (short)f2bf(a1.z); A0[7] = (short)f2bf(a1.w);
            A1[0] = (short)f2bf(a2.x); A1[1] = (short)f2bf(a2.y); A1[2] = (short)f2bf(a2.z); A1[3] = (short)f2bf(a2.w);
            A1[4] = (short)f2bf(a3.x); A1[5] = (short)f2bf(a3.y); A1[6] = (short)f2bf(a3.z); A1[7] = (short)f2bf(a3.w);

            int ra0 = __shfl(obj, g4 * 4 + 0);
            int ra1 = __shfl(obj, g4 * 4 + 1);
            int ra2 = __shfl(obj, g4 * 4 + 2);
            int ra3 = __shfl(obj, g4 * 4 + 3);
            bool v0 = (g4 * 4 + 0) < n;
            bool v1 = (g4 * 4 + 1) < n;
            bool v2 = (g4 * 4 + 2) < n;
            bool v3 = (g4 * 4 + 3) < n;

            #pragma unroll
            for (int f = 0; f < 16; ++f) {
                float pv = p.P[(size_t)seg * 1024 + n0 + f * 16 + ln];
                const unsigned short* wr = &p.w1cT[(size_t)(n0 + f * 16 + ln) * 64];
                bf16x8 b0 = *(const bf16x8*)&wr[kb];
                bf16x8 b1 = *(const bf16x8*)&wr[32 + kb];
                f32x4 d = {0.f, 0.f, 0.f, 0.f};
                d = __builtin_amdgcn_mfma_f32_16x16x32_bf16(A0, b0, d, 0, 0, 0);
                d = __builtin_amdgcn_mfma_f32_16x16x32_bf16(A1, b1, d, 0, 0, 0);
                int col = n0 + f * 16 + ln;
                float q0 = p.Q[(size_t)ra0 * 1024 + col];
                float q1 = p.Q[(size_t)ra1 * 1024 + col];
                float q2 = p.Q[(size_t)ra2 * 1024 + col];
                float q3 = p.Q[(size_t)ra3 * 1024 + col];
                float h = 0.f;
                h += v0 ? fmaxf(d[0] + pv + q0, 0.f) : 0.f;
                h += v1 ? fmaxf(d[1] + pv + q1, 0.f) : 0.f;
                h += v2 ? fmaxf(d[2] + pv + q2, 0.f) : 0.f;
                h += v3 ? fmaxf(d[3] + pv + q3, 0.f) : 0.f;
                h += __shfl_xor(h, 16);
                h += __shfl_xor(h, 32);
                if (l < 16) atomicAdd(&p.HS[(size_t)seg * 1024 + n0 + f * 16 + l], h);
            }
        }
    } else {
        copy_role(p.csrc, p.cdst, OFF_D, LEN_D, NC, bid - GC);
    }
    grid.sync();

    // ================= Phase E: out GEMM + remaining copy =================
    if (bid < 128) {
        int m0 = (bid >> 3) * 64, n0 = (bid & 7) * 64;
        int w = tid >> 6, l = tid & 63;
        int ln = l & 15, kb = (l >> 4) * 8;
        int row = m0 + w * 16 + ln;
        f32x4 acc[4] = {};
        for (int k0 = 0; k0 < 1024; k0 += 32) {
            const float* hp = &p.HS[(size_t)row * 1024 + k0 + kb];
            float4 h0 = *(const float4*)&hp[0];
            float4 h1 = *(const float4*)&hp[4];
            bf16x8 a;
            a[0] = (short)f2bf(h0.x); a[1] = (short)f2bf(h0.y); a[2] = (short)f2bf(h0.z); a[3] = (short)f2bf(h0.w);
            a[4] = (short)f2bf(h1.x); a[5] = (short)f2bf(h1.y); a[6] = (short)f2bf(h1.z); a[7] = (short)f2bf(h1.w);
            #pragma unroll
            for (int f = 0; f < 4; ++f) {
                bf16x8 b = *(const bf16x8*)&p.w2T[(size_t)(n0 + f * 16 + ln) * 1024 + k0 + kb];
                acc[f] = __builtin_amdgcn_mfma_f32_16x16x32_bf16(a, b, acc[f], 0, 0, 0);
            }
        }
        int mr = m0 + w * 16 + (l >> 4) * 4;
        float cv[4], inv[4];
        #pragma unroll
        for (int r = 0; r < 4; ++r) {
            float c = (float)p.counts[mr + r];
            cv[r] = c;
            inv[r] = 1.0f / (1.0f + c);
        }
        #pragma unroll
        for (int f = 0; f < 4; ++f) {
            int nn = n0 + f * 16 + ln;
            float b2v = p.b2[nn];
            #pragma unroll
            for (int r = 0; r < 4; ++r) {
                float fv = p.feats[(size_t)(mr + r) * 512 + nn];
                p.out_feats[(size_t)(mr + r) * 512 + nn] = (fv + acc[f][r] + cv[r] * b2v) * inv[r];
            }
        }
    } else {
        copy_role(p.csrc, p.cdst, OFF_E, LEN_E, G - 128, bid - 128);
    }
}

extern "C" void kernel_launch(void* const* d_in, const int* in_sizes, int n_in,
                              void* d_out, int out_size, void* d_ws, size_t ws_size,
                              hipStream_t stream) {
    const float* feats = (const float*)d_in[0];
    const float* bb    = (const float*)d_in[1];
    const int*   pairs = (const int*)d_in[2];
    const float* W1    = (const float*)d_in[3];
    const float* b1    = (const float*)d_in[4];
    const float* W2    = (const float*)d_in[5];
    const float* b2    = (const float*)d_in[6];

    float* out        = (float*)d_out;
    float* out_feats  = out;
    float* out_bb     = out + (size_t)N_OBJ * 512;
    float* out_pairs  = out + (size_t)N_OBJ * 512 + (size_t)N_OBJ * N_OBJ * 64;

    // ---- workspace layout (~13.4 MB) ----
    // [0,4MB): featsb [0,1M) + w1pqT [1M,3M) + pad — dead after phase C; HS (f32 4MB) aliases it
    char* w = (char*)d_ws;
    Params p;
    p.feats = feats; p.bb = bb; p.pairs = pairs;
    p.W1 = W1; p.b1 = b1; p.W2 = W2; p.b2 = b2;
    p.out_feats = out_feats; p.out_pairs = out_pairs;
    p.csrc = (const float4*)bb; p.cdst = (float4*)out_bb;
    p.featsb = (unsigned short*)w;
    p.w1pqT  = (unsigned short*)(w + (1u << 20));
    p.HS     = (float*)w;
    p.w1cT   = (unsigned short*)(w + (4u << 20));
    p.w2T    = (unsigned short*)(w + (4u << 20) + (128u << 10));
    p.P      = (float*)(w + (5u << 20) + (128u << 10));
    p.Q      = (float*)(w + (9u << 20) + (128u << 10));
    char* ints = w + (13u << 20) + (128u << 10);
    p.counts  = (int*)ints;
    p.cursor  = (int*)(ints + 4096);
    p.csr_obj = (int*)(ints + 8192);
    p.brec    = (unsigned*)(ints + 8192 + 131072);
    p.bcnt    = (int*)(ints + 8192 + 131072 + 16384);

    hipMemsetAsync(p.counts, 0, 4096, stream);

    int bpc = 0;
    hipError_t oe = hipOccupancyMaxActiveBlocksPerMultiprocessor(&bpc, (const void*)k_fused, 256, 0);
    if (oe != hipSuccess || bpc < 1) bpc = 2;
    int G = bpc * 256;
    if (G > 1024) G = 1024;
    if (G < 256)  G = 256;

    void* args[] = { (void*)&p };
    hipLaunchCooperativeKernel((const void*)k_fused, dim3(G), dim3(256), args, 0, stream);
}

// Round 6
// 230.452 us; speedup vs baseline: 2.4562x; 2.4562x over previous
//
#include <hip/hip_runtime.h>

#define N_OBJ 1024
#define E_P   32768

typedef float f32x4 __attribute__((ext_vector_type(4)));
typedef short bf16x8 __attribute__((ext_vector_type(8)));
typedef unsigned short u16x4 __attribute__((ext_vector_type(4)));

__device__ __forceinline__ unsigned short f2bf(float f) {
    unsigned u = __float_as_uint(f);
    u = u + 0x7FFFu + ((u >> 16) & 1u);   // RNE
    return (unsigned short)(u >> 16);
}

// ---- copy split (float4 units): total = 1024*1024*64/4 = 16777216 ----
#define OFF_A    0
#define LEN_A    2097152
#define OFF_SCAN (OFF_A + LEN_A)
#define LEN_SCAN 1048576
#define OFF_PQ   (OFF_SCAN + LEN_SCAN)
#define LEN_PQ   3145728
#define OFF_SEG  (OFF_PQ + LEN_PQ)
#define LEN_SEG  7340032
#define OFF_OUT  (OFF_SEG + LEN_SEG)
#define LEN_OUT  3145728

__device__ __forceinline__ void copy_role(const float4* __restrict__ src,
                                          float4* __restrict__ dst,
                                          int off, int len, int nb, int cb) {
    int stride = nb * 256;
    int i = off + cb * 256 + threadIdx.x;
    int end = off + len;
    for (; i + stride < end; i += 2 * stride) {
        float4 a = src[i];
        float4 b = src[i + stride];
        dst[i] = a;
        dst[i + stride] = b;
    }
    if (i < end) dst[i] = src[i];
}

// ================= k_a: weight transpose/convert + featsb + pairs/hist + copy =================
// grid 3168: bid%3==2 -> copy (1056); else job = (bid/3)*2 + bid%3  (0..2111)
__global__ __launch_bounds__(256) void k_a(const float* __restrict__ W1,
                                           const float* __restrict__ W2,
                                           const float* __restrict__ feats,
                                           const int* __restrict__ pairs,
                                           unsigned short* __restrict__ w1pqT,
                                           unsigned short* __restrict__ w1cT,
                                           unsigned short* __restrict__ w2T,
                                           unsigned short* __restrict__ featsb,
                                           float* __restrict__ out_pairs,
                                           int* __restrict__ counts,
                                           const float4* __restrict__ csrc,
                                           float4* __restrict__ cdst) {
    int bid = blockIdx.x, tid = threadIdx.x;
    if ((bid % 3) == 2) { copy_role(csrc, cdst, OFF_A, LEN_A, 1056, bid / 3); return; }
    int job = (bid / 3) * 2 + (bid % 3);
    if (job >= 1856) {                 // pairs passthrough + histogram
        int i = (job - 1856) * 256 + tid;
        out_pairs[i] = (float)pairs[i];
        if (i < E_P) atomicAdd(&counts[pairs[2 * i]], 1);
        return;
    }
    if (job >= 1600) {                 // featsb straight convert
        int base = (job - 1600) * 2048 + tid * 8;
        float4 v0 = *(const float4*)&feats[base];
        float4 v1 = *(const float4*)&feats[base + 4];
        u16x4 o0 = { f2bf(v0.x), f2bf(v0.y), f2bf(v0.z), f2bf(v0.w) };
        u16x4 o1 = { f2bf(v1.x), f2bf(v1.y), f2bf(v1.z), f2bf(v1.w) };
        *(u16x4*)&featsb[base] = o0;
        *(u16x4*)&featsb[base + 4] = o1;
        return;
    }
    const float* in; unsigned short* out;
    int LDI, LDO, r0, c0, nbase, kbase;
    if (job < 1024) {                  // W1[0:1024] -> w1pqT [2048][512]
        r0 = (job >> 5) * 32; c0 = (job & 31) * 32;
        in = W1; LDI = 1024; out = w1pqT; LDO = 512;
        nbase = c0 + (r0 >= 512 ? 1024 : 0); kbase = r0 & 511;
    } else if (job < 1088) {           // W1[1024:1088] -> w1cT [1024][64]
        int t = job - 1024; r0 = 1024 + (t >> 5) * 32; c0 = (t & 31) * 32;
        in = W1; LDI = 1024; out = w1cT; LDO = 64;
        nbase = c0; kbase = r0 - 1024;
    } else {                           // W2 [1024][512] -> w2T [512][1024]
        int t = job - 1088; r0 = (t >> 4) * 32; c0 = (t & 15) * 32;
        in = W2; LDI = 512; out = w2T; LDO = 1024;
        nbase = c0; kbase = r0;
    }
    __shared__ float lds[32][33];
    int ti = tid >> 3, tj = (tid & 7) * 4;
    float4 v = *(const float4*)&in[(size_t)(r0 + ti) * LDI + c0 + tj];
    lds[ti][tj] = v.x; lds[ti][tj + 1] = v.y; lds[ti][tj + 2] = v.z; lds[ti][tj + 3] = v.w;
    __syncthreads();
    int oc = tid >> 3, oj = (tid & 7) * 4;
    u16x4 o = { f2bf(lds[oj][oc]), f2bf(lds[oj + 1][oc]),
                f2bf(lds[oj + 2][oc]), f2bf(lds[oj + 3][oc]) };
    *(u16x4*)&out[(size_t)(nbase + oc) * LDO + kbase + oj] = o;
}

// ================= k_scan: block 0 scans + builds batch32 records; rest copy =================
__global__ __launch_bounds__(256) void k_scan(const int* __restrict__ counts,
                                              int* __restrict__ cursor,
                                              unsigned* __restrict__ brec,
                                              int* __restrict__ bcnt,
                                              const float4* __restrict__ csrc,
                                              float4* __restrict__ cdst) {
    int bid = blockIdx.x, tid = threadIdx.x;
    if (bid != 0) { copy_role(csrc, cdst, OFF_SCAN, LEN_SCAN, 1024, bid - 1); return; }
    __shared__ int buf[2][256];
    int c[4]; int s = 0;
    #pragma unroll
    for (int i = 0; i < 4; ++i) { c[i] = counts[tid * 4 + i]; s += c[i]; }
    buf[0][tid] = s;
    __syncthreads();
    int sel = 0;
    for (int d = 1; d < 256; d <<= 1) {
        int v = buf[sel][tid];
        if (tid >= d) v += buf[sel][tid - d];
        buf[sel ^ 1][tid] = v;
        sel ^= 1;
        __syncthreads();
    }
    int base = buf[sel][tid] - s;      // exclusive prefix of pair counts
    int run = base;
    #pragma unroll
    for (int i = 0; i < 4; ++i) { cursor[tid * 4 + i] = run; run += c[i]; }
    // batch-32 records
    int nb[4]; int t = 0;
    #pragma unroll
    for (int i = 0; i < 4; ++i) { nb[i] = (c[i] + 31) >> 5; t += nb[i]; }
    __syncthreads();
    buf[0][tid] = t;
    __syncthreads();
    sel = 0;
    for (int d = 1; d < 256; d <<= 1) {
        int v = buf[sel][tid];
        if (tid >= d) v += buf[sel][tid - d];
        buf[sel ^ 1][tid] = v;
        sel ^= 1;
        __syncthreads();
    }
    int bpos = buf[sel][tid] - t;
    int run2 = base;
    #pragma unroll
    for (int i = 0; i < 4; ++i) {
        int seg = tid * 4 + i;
        for (int k = 0; k < nb[i]; ++k) {
            int st = run2 + k * 32;
            int cnt = c[i] - k * 32; if (cnt > 32) cnt = 32;
            brec[bpos++] = (unsigned)st | ((unsigned)seg << 16) | ((unsigned)(cnt - 1) << 26);
        }
        run2 += c[i];
    }
    if (tid == 255) bcnt[0] = bpos;
}

// ================= k_pq: scatter(csr_obj) + PQ GEMM + copy =================
// grid 1664: bid>=1536 -> scatter (128); bid%3<2 -> copy (1024); else gemm (512)
__global__ __launch_bounds__(256) void k_pq(const unsigned short* __restrict__ featsb,
                                            const unsigned short* __restrict__ w1pqT,
                                            const float* __restrict__ b1,
                                            float* __restrict__ P, float* __restrict__ Q,
                                            const int* __restrict__ pairs,
                                            int* __restrict__ cursor,
                                            int* __restrict__ csr_obj,
                                            const float4* __restrict__ csrc,
                                            float4* __restrict__ cdst) {
    int bid = blockIdx.x;
    if (bid >= 1536) {                 // scatter: store obj directly
        int e = (bid - 1536) * 256 + threadIdx.x;
        int sidx = pairs[2 * e];
        int pos = atomicAdd(&cursor[sidx], 1);
        csr_obj[pos] = pairs[2 * e + 1];
        return;
    }
    if ((bid % 3) < 2) { copy_role(csrc, cdst, OFF_PQ, LEN_PQ, 1024, (bid / 3) * 2 + (bid % 3)); return; }
    int job = bid / 3;
    int m0 = (job >> 5) * 64, n0 = (job & 31) * 64;
    int tid = threadIdx.x, w = tid >> 6, l = tid & 63;
    int ln = l & 15, kb = (l >> 4) * 8;
    int row = m0 + w * 16 + ln;
    f32x4 acc[4] = {};
    for (int k0 = 0; k0 < 512; k0 += 32) {
        bf16x8 a = *(const bf16x8*)&featsb[(size_t)row * 512 + k0 + kb];
        #pragma unroll
        for (int f = 0; f < 4; ++f) {
            bf16x8 b = *(const bf16x8*)&w1pqT[(size_t)(n0 + f * 16 + ln) * 512 + k0 + kb];
            acc[f] = __builtin_amdgcn_mfma_f32_16x16x32_bf16(a, b, acc[f], 0, 0, 0);
        }
    }
    int mr = m0 + w * 16 + (l >> 4) * 4;
    if (n0 < 1024) {
        #pragma unroll
        for (int f = 0; f < 4; ++f) {
            int n = n0 + f * 16 + ln;
            float b1v = b1[n];
            #pragma unroll
            for (int r = 0; r < 4; ++r)
                P[(size_t)(mr + r) * 1024 + n] = acc[f][r] + b1v;
        }
    } else {
        #pragma unroll
        for (int f = 0; f < 4; ++f) {
            int n = n0 - 1024 + f * 16 + ln;
            #pragma unroll
            for (int r = 0; r < 4; ++r)
                Q[(size_t)(mr + r) * 1024 + n] = acc[f][r];
        }
    }
}

// ================= k_seg: one 32-pair batch per block + copy =================
// grid 4096: bid%2==0 -> copy (2048); else batch slot b=bid/2 (2048 slots)
__global__ __launch_bounds__(256) void k_seg(const int* __restrict__ csr_obj,
                                             const unsigned* __restrict__ brec,
                                             const int* __restrict__ bcnt,
                                             const float* __restrict__ bb,
                                             const unsigned short* __restrict__ w1cT,
                                             const float* __restrict__ P,
                                             const float* __restrict__ Q,
                                             float* __restrict__ HS,
                                             const float4* __restrict__ csrc,
                                             float4* __restrict__ cdst) {
    int bid = blockIdx.x;
    if ((bid % 2) == 0) { copy_role(csrc, cdst, OFF_SEG, LEN_SEG, 2048, bid / 2); return; }
    int b = bid / 2;
    if (b >= bcnt[0]) return;
    unsigned rec = brec[b];
    const int start = rec & 0xFFFF;
    const int seg = (rec >> 16) & 0x3FF;
    const int n = ((rec >> 26) & 31) + 1;

    const int tid = threadIdx.x, w = tid >> 6, l = tid & 63;
    const int ln = l & 15, g4 = l >> 4, kb = g4 * 8;
    const int n0 = w * 256;
    const int nA = n < 16 ? n : 16;
    const int nB = n - 16;

    // set A: pairs [0..nA), set B: pairs [16..n)
    int iA = start + (ln < nA ? ln : nA - 1);
    int iB = (nB > 0) ? (start + 16 + (ln < nB ? ln : nB - 1)) : iA;
    int objA = csr_obj[iA];
    int objB = csr_obj[iB];

    const float* brA = &bb[((size_t)seg * 1024 + (size_t)objA) * 64];
    const float* brB = &bb[((size_t)seg * 1024 + (size_t)objB) * 64];
    float4 a0 = *(const float4*)&brA[kb];
    float4 a1 = *(const float4*)&brA[kb + 4];
    float4 a2 = *(const float4*)&brA[32 + kb];
    float4 a3 = *(const float4*)&brA[32 + kb + 4];
    float4 c0 = *(const float4*)&brB[kb];
    float4 c1 = *(const float4*)&brB[kb + 4];
    float4 c2 = *(const float4*)&brB[32 + kb];
    float4 c3 = *(const float4*)&brB[32 + kb + 4];
    bf16x8 A0a, A1a, A0b, A1b;
    A0a[0] = (short)f2bf(a0.x); A0a[1] = (short)f2bf(a0.y); A0a[2] = (short)f2bf(a0.z); A0a[3] = (short)f2bf(a0.w);
    A0a[4] = (short)f2bf(a1.x); A0a[5] = (short)f2bf(a1.y); A0a[6] = (short)f2bf(a1.z); A0a[7] = (short)f2bf(a1.w);
    A1a[0] = (short)f2bf(a2.x); A1a[1] = (short)f2bf(a2.y); A1a[2] = (short)f2bf(a2.z); A1a[3] = (short)f2bf(a2.w);
    A1a[4] = (short)f2bf(a3.x); A1a[5] = (short)f2bf(a3.y); A1a[6] = (short)f2bf(a3.z); A1a[7] = (short)f2bf(a3.w);
    A0b[0] = (short)f2bf(c0.x); A0b[1] = (short)f2bf(c0.y); A0b[2] = (short)f2bf(c0.z); A0b[3] = (short)f2bf(c0.w);
    A0b[4] = (short)f2bf(c1.x); A0b[5] = (short)f2bf(c1.y); A0b[6] = (short)f2bf(c1.z); A0b[7] = (short)f2bf(c1.w);
    A1b[0] = (short)f2bf(c2.x); A1b[1] = (short)f2bf(c2.y); A1b[2] = (short)f2bf(c2.z); A1b[3] = (short)f2bf(c2.w);
    A1b[4] = (short)f2bf(c3.x); A1b[5] = (short)f2bf(c3.y); A1b[6] = (short)f2bf(c3.z); A1b[7] = (short)f2bf(c3.w);

    int raA0 = __shfl(objA, g4 * 4 + 0), raA1 = __shfl(objA, g4 * 4 + 1);
    int raA2 = __shfl(objA, g4 * 4 + 2), raA3 = __shfl(objA, g4 * 4 + 3);
    int raB0 = __shfl(objB, g4 * 4 + 0), raB1 = __shfl(objB, g4 * 4 + 1);
    int raB2 = __shfl(objB, g4 * 4 + 2), raB3 = __shfl(objB, g4 * 4 + 3);
    bool vA0 = (g4 * 4 + 0) < nA, vA1 = (g4 * 4 + 1) < nA;
    bool vA2 = (g4 * 4 + 2) < nA, vA3 = (g4 * 4 + 3) < nA;
    bool vB0 = (g4 * 4 + 0) < nB, vB1 = (g4 * 4 + 1) < nB;
    bool vB2 = (g4 * 4 + 2) < nB, vB3 = (g4 * 4 + 3) < nB;

    #pragma unroll 4
    for (int f = 0; f < 16; ++f) {
        int col = n0 + f * 16 + ln;
        const unsigned short* wr = &w1cT[(size_t)col * 64];
        bf16x8 b0 = *(const bf16x8*)&wr[kb];
        bf16x8 b1 = *(const bf16x8*)&wr[32 + kb];
        f32x4 dA = {0.f, 0.f, 0.f, 0.f};
        dA = __builtin_amdgcn_mfma_f32_16x16x32_bf16(A0a, b0, dA, 0, 0, 0);
        dA = __builtin_amdgcn_mfma_f32_16x16x32_bf16(A1a, b1, dA, 0, 0, 0);
        f32x4 dB = {0.f, 0.f, 0.f, 0.f};
        dB = __builtin_amdgcn_mfma_f32_16x16x32_bf16(A0b, b0, dB, 0, 0, 0);
        dB = __builtin_amdgcn_mfma_f32_16x16x32_bf16(A1b, b1, dB, 0, 0, 0);
        float pv = P[(size_t)seg * 1024 + col];
        float qA0 = Q[(size_t)raA0 * 1024 + col];
        float qA1 = Q[(size_t)raA1 * 1024 + col];
        float qA2 = Q[(size_t)raA2 * 1024 + col];
        float qA3 = Q[(size_t)raA3 * 1024 + col];
        float qB0 = Q[(size_t)raB0 * 1024 + col];
        float qB1 = Q[(size_t)raB1 * 1024 + col];
        float qB2 = Q[(size_t)raB2 * 1024 + col];
        float qB3 = Q[(size_t)raB3 * 1024 + col];
        float h = 0.f;
        h += vA0 ? fmaxf(dA[0] + pv + qA0, 0.f) : 0.f;
        h += vA1 ? fmaxf(dA[1] + pv + qA1, 0.f) : 0.f;
        h += vA2 ? fmaxf(dA[2] + pv + qA2, 0.f) : 0.f;
        h += vA3 ? fmaxf(dA[3] + pv + qA3, 0.f) : 0.f;
        h += vB0 ? fmaxf(dB[0] + pv + qB0, 0.f) : 0.f;
        h += vB1 ? fmaxf(dB[1] + pv + qB1, 0.f) : 0.f;
        h += vB2 ? fmaxf(dB[2] + pv + qB2, 0.f) : 0.f;
        h += vB3 ? fmaxf(dB[3] + pv + qB3, 0.f) : 0.f;
        h += __shfl_xor(h, 16);
        h += __shfl_xor(h, 32);
        if (l < 16) atomicAdd(&HS[(size_t)seg * 1024 + n0 + f * 16 + l], h);
    }
}

// ================= k_out: (feats + HS@W2 + cnt*b2)/(1+cnt) + copy =================
// grid 1152: bid%9==8 -> gemm (128); else copy (1024)
__global__ __launch_bounds__(256) void k_out(const float* __restrict__ HS,
                                             const unsigned short* __restrict__ w2T,
                                             const float* __restrict__ feats,
                                             const float* __restrict__ b2,
                                             const int* __restrict__ counts,
                                             float* __restrict__ out0,
                                             const float4* __restrict__ csrc,
                                             float4* __restrict__ cdst) {
    int bid = blockIdx.x;
    if ((bid % 9) != 8) { copy_role(csrc, cdst, OFF_OUT, LEN_OUT, 1024, (bid / 9) * 8 + (bid % 9)); return; }
    int job = bid / 9;
    int m0 = (job >> 3) * 64, n0 = (job & 7) * 64;
    int tid = threadIdx.x, w = tid >> 6, l = tid & 63;
    int ln = l & 15, kb = (l >> 4) * 8;
    int row = m0 + w * 16 + ln;
    f32x4 acc[4] = {};
    for (int k0 = 0; k0 < 1024; k0 += 32) {
        const float* hp = &HS[(size_t)row * 1024 + k0 + kb];
        float4 h0 = *(const float4*)&hp[0];
        float4 h1 = *(const float4*)&hp[4];
        bf16x8 a;
        a[0] = (short)f2bf(h0.x); a[1] = (short)f2bf(h0.y); a[2] = (short)f2bf(h0.z); a[3] = (short)f2bf(h0.w);
        a[4] = (short)f2bf(h1.x); a[5] = (short)f2bf(h1.y); a[6] = (short)f2bf(h1.z); a[7] = (short)f2bf(h1.w);
        #pragma unroll
        for (int f = 0; f < 4; ++f) {
            bf16x8 b = *(const bf16x8*)&w2T[(size_t)(n0 + f * 16 + ln) * 1024 + k0 + kb];
            acc[f] = __builtin_amdgcn_mfma_f32_16x16x32_bf16(a, b, acc[f], 0, 0, 0);
        }
    }
    int mr = m0 + w * 16 + (l >> 4) * 4;
    float cv[4], inv[4];
    #pragma unroll
    for (int r = 0; r < 4; ++r) {
        float c = (float)counts[mr + r];
        cv[r] = c;
        inv[r] = 1.0f / (1.0f + c);
    }
    #pragma unroll
    for (int f = 0; f < 4; ++f) {
        int n = n0 + f * 16 + ln;
        float b2v = b2[n];
        #pragma unroll
        for (int r = 0; r < 4; ++r) {
            float fv = feats[(size_t)(mr + r) * 512 + n];
            out0[(size_t)(mr + r) * 512 + n] = (fv + acc[f][r] + cv[r] * b2v) * inv[r];
        }
    }
}

extern "C" void kernel_launch(void* const* d_in, const int* in_sizes, int n_in,
                              void* d_out, int out_size, void* d_ws, size_t ws_size,
                              hipStream_t stream) {
    const float* feats = (const float*)d_in[0];
    const float* bb    = (const float*)d_in[1];
    const int*   pairs = (const int*)d_in[2];
    const float* W1    = (const float*)d_in[3];
    const float* b1    = (const float*)d_in[4];
    const float* W2    = (const float*)d_in[5];
    const float* b2    = (const float*)d_in[6];

    float* out        = (float*)d_out;
    float* out_feats  = out;
    float* out_bb     = out + (size_t)N_OBJ * 512;
    float* out_pairs  = out + (size_t)N_OBJ * 512 + (size_t)N_OBJ * N_OBJ * 64;

    // ---- workspace layout (~13.4 MB) ----
    // [0,4MB): featsb [0,1M) + w1pqT [1M,3M) — dead after k_pq; HS (f32 4MB) aliases it
    char* w = (char*)d_ws;
    unsigned short* featsb = (unsigned short*)w;
    unsigned short* w1pqT  = (unsigned short*)(w + (1u << 20));
    float*          HS     = (float*)w;
    unsigned short* w1cT   = (unsigned short*)(w + (4u << 20));
    unsigned short* w2T    = (unsigned short*)(w + (4u << 20) + (128u << 10));
    float* P = (float*)(w + (5u << 20) + (128u << 10));
    float* Q = (float*)(w + (9u << 20) + (128u << 10));
    char* ints = w + (13u << 20) + (128u << 10);
    int*      counts  = (int*)ints;
    int*      cursor  = (int*)(ints + 4096);
    int*      csr_obj = (int*)(ints + 8192);
    unsigned* brec    = (unsigned*)(ints + 8192 + 131072);
    int*      bcnt    = (int*)(ints + 8192 + 131072 + 16384);

    const float4* cbb  = (const float4*)bb;
    float4*       cobb = (float4*)out_bb;

    hipMemsetAsync(counts, 0, 4096, stream);

    k_a<<<3168, 256, 0, stream>>>(W1, W2, feats, pairs, w1pqT, w1cT, w2T, featsb,
                                  out_pairs, counts, cbb, cobb);
    k_scan<<<1025, 256, 0, stream>>>(counts, cursor, brec, bcnt, cbb, cobb);
    k_pq<<<1664, 256, 0, stream>>>(featsb, w1pqT, b1, P, Q, pairs, cursor, csr_obj, cbb, cobb);

    hipMemsetAsync(HS, 0, (size_t)N_OBJ * 1024 * sizeof(float), stream);

    k_seg<<<4096, 256, 0, stream>>>(csr_obj, brec, bcnt, bb, w1cT, P, Q, HS, cbb, cobb);
    k_out<<<1152, 256, 0, stream>>>(HS, w2T, feats, b2, counts, out_feats, cbb, cobb);
}

// Round 7
// 229.749 us; speedup vs baseline: 2.4637x; 1.0031x over previous
//
#include <hip/hip_runtime.h>

#define N_OBJ 1024
#define E_P   32768

typedef float f32x4 __attribute__((ext_vector_type(4)));
typedef short bf16x8 __attribute__((ext_vector_type(8)));
typedef unsigned short u16x4 __attribute__((ext_vector_type(4)));

__device__ __forceinline__ unsigned short f2bf(float f) {
    unsigned u = __float_as_uint(f);
    u = u + 0x7FFFu + ((u >> 16) & 1u);   // RNE
    return (unsigned short)(u >> 16);
}

// ---- copy split (float4 units): total = 1024*1024*64/4 = 16777216 ----
#define OFF_A    0
#define LEN_A    2097152
#define OFF_B    (OFF_A + LEN_A)
#define LEN_B    2621440
#define OFF_SEG  (OFF_B + LEN_B)
#define LEN_SEG  9437184
#define OFF_OUT  (OFF_SEG + LEN_SEG)
#define LEN_OUT  2621440

__device__ __forceinline__ void copy_role(const float4* __restrict__ src,
                                          float4* __restrict__ dst,
                                          int off, int len, int nb, int cb) {
    int stride = nb * 256;
    int i = off + cb * 256 + threadIdx.x;
    int end = off + len;
    for (; i + stride < end; i += 2 * stride) {
        float4 a = src[i];
        float4 b = src[i + stride];
        dst[i] = a;
        dst[i + stride] = b;
    }
    if (i < end) dst[i] = src[i];
}

// ================= k_a: weight transpose/convert + featsb + pairs/hist/rank + copy =================
// grid 3168: bid%3==2 -> copy (1056); else job = (bid/3)*2 + bid%3  (0..2111)
__global__ __launch_bounds__(256) void k_a(const float* __restrict__ W1,
                                           const float* __restrict__ W2,
                                           const float* __restrict__ feats,
                                           const int* __restrict__ pairs,
                                           unsigned short* __restrict__ w1pqT,
                                           unsigned short* __restrict__ w1cT,
                                           unsigned short* __restrict__ w2T,
                                           unsigned short* __restrict__ featsb,
                                           float* __restrict__ out_pairs,
                                           int* __restrict__ counts,
                                           int* __restrict__ rank,
                                           const float4* __restrict__ csrc,
                                           float4* __restrict__ cdst) {
    int bid = blockIdx.x, tid = threadIdx.x;
    if ((bid % 3) == 2) { copy_role(csrc, cdst, OFF_A, LEN_A, 1056, bid / 3); return; }
    int job = (bid / 3) * 2 + (bid % 3);
    if (job >= 1856) {                 // pairs passthrough + histogram + rank
        int i = (job - 1856) * 256 + tid;
        out_pairs[i] = (float)pairs[i];
        if (i < E_P) rank[i] = atomicAdd(&counts[pairs[2 * i]], 1);
        return;
    }
    if (job >= 1600) {                 // featsb straight convert
        int base = (job - 1600) * 2048 + tid * 8;
        float4 v0 = *(const float4*)&feats[base];
        float4 v1 = *(const float4*)&feats[base + 4];
        u16x4 o0 = { f2bf(v0.x), f2bf(v0.y), f2bf(v0.z), f2bf(v0.w) };
        u16x4 o1 = { f2bf(v1.x), f2bf(v1.y), f2bf(v1.z), f2bf(v1.w) };
        *(u16x4*)&featsb[base] = o0;
        *(u16x4*)&featsb[base + 4] = o1;
        return;
    }
    const float* in; unsigned short* out;
    int LDI, LDO, r0, c0, nbase, kbase;
    if (job < 1024) {                  // W1[0:1024] -> w1pqT [2048][512]
        r0 = (job >> 5) * 32; c0 = (job & 31) * 32;
        in = W1; LDI = 1024; out = w1pqT; LDO = 512;
        nbase = c0 + (r0 >= 512 ? 1024 : 0); kbase = r0 & 511;
    } else if (job < 1088) {           // W1[1024:1088] -> w1cT [1024][64]
        int t = job - 1024; r0 = 1024 + (t >> 5) * 32; c0 = (t & 31) * 32;
        in = W1; LDI = 1024; out = w1cT; LDO = 64;
        nbase = c0; kbase = r0 - 1024;
    } else {                           // W2 [1024][512] -> w2T [512][1024]
        int t = job - 1088; r0 = (t >> 4) * 32; c0 = (t & 15) * 32;
        in = W2; LDI = 512; out = w2T; LDO = 1024;
        nbase = c0; kbase = r0;
    }
    __shared__ float lds[32][33];
    int ti = tid >> 3, tj = (tid & 7) * 4;
    float4 v = *(const float4*)&in[(size_t)(r0 + ti) * LDI + c0 + tj];
    lds[ti][tj] = v.x; lds[ti][tj + 1] = v.y; lds[ti][tj + 2] = v.z; lds[ti][tj + 3] = v.w;
    __syncthreads();
    int oc = tid >> 3, oj = (tid & 7) * 4;
    u16x4 o = { f2bf(lds[oj][oc]), f2bf(lds[oj + 1][oc]),
                f2bf(lds[oj + 2][oc]), f2bf(lds[oj + 3][oc]) };
    *(u16x4*)&out[(size_t)(nbase + oc) * LDO + kbase + oj] = o;
}

// ================= k_b: brec-build + scatter (redundant in-block scan) + PQ GEMM + copy =================
// grid 1344: bid even -> copy (672); bid odd -> role = bid>>1:
//   role 0 = brec builder; 1..128 = scatter; 129..640 = GEMM; rest idle
__global__ __launch_bounds__(256) void k_b(const int* __restrict__ counts,
                                           const int* __restrict__ rank,
                                           const int* __restrict__ pairs,
                                           int* __restrict__ csr_obj,
                                           unsigned* __restrict__ brec,
                                           int* __restrict__ bcnt,
                                           const unsigned short* __restrict__ featsb,
                                           const unsigned short* __restrict__ w1pqT,
                                           const float* __restrict__ b1,
                                           float* __restrict__ P, float* __restrict__ Q,
                                           const float4* __restrict__ csrc,
                                           float4* __restrict__ cdst) {
    int bid = blockIdx.x, tid = threadIdx.x;
    if ((bid & 1) == 0) { copy_role(csrc, cdst, OFF_B, LEN_B, 672, bid >> 1); return; }
    int role = bid >> 1;
    if (role >= 641) return;

    if (role >= 129) {                 // ---- PQ GEMM tile ----
        int job = role - 129;
        int m0 = (job >> 5) * 64, n0 = (job & 31) * 64;
        int w = tid >> 6, l = tid & 63;
        int ln = l & 15, kb = (l >> 4) * 8;
        int row = m0 + w * 16 + ln;
        f32x4 acc[4] = {};
        for (int k0 = 0; k0 < 512; k0 += 32) {
            bf16x8 a = *(const bf16x8*)&featsb[(size_t)row * 512 + k0 + kb];
            #pragma unroll
            for (int f = 0; f < 4; ++f) {
                bf16x8 b = *(const bf16x8*)&w1pqT[(size_t)(n0 + f * 16 + ln) * 512 + k0 + kb];
                acc[f] = __builtin_amdgcn_mfma_f32_16x16x32_bf16(a, b, acc[f], 0, 0, 0);
            }
        }
        int mr = m0 + w * 16 + (l >> 4) * 4;
        if (n0 < 1024) {
            #pragma unroll
            for (int f = 0; f < 4; ++f) {
                int n = n0 + f * 16 + ln;
                float b1v = b1[n];
                #pragma unroll
                for (int r = 0; r < 4; ++r)
                    P[(size_t)(mr + r) * 1024 + n] = acc[f][r] + b1v;
            }
        } else {
            #pragma unroll
            for (int f = 0; f < 4; ++f) {
                int n = n0 - 1024 + f * 16 + ln;
                #pragma unroll
                for (int r = 0; r < 4; ++r)
                    Q[(size_t)(mr + r) * 1024 + n] = acc[f][r];
            }
        }
        return;
    }

    // ---- roles 0..128: need exclusive scan of counts in LDS ----
    __shared__ int sbuf[2][256];
    __shared__ int soff[1024];
    int c[4]; int s = 0;
    #pragma unroll
    for (int i = 0; i < 4; ++i) { c[i] = counts[tid * 4 + i]; s += c[i]; }
    sbuf[0][tid] = s;
    __syncthreads();
    int sel = 0;
    for (int d = 1; d < 256; d <<= 1) {
        int v = sbuf[sel][tid];
        if (tid >= d) v += sbuf[sel][tid - d];
        sbuf[sel ^ 1][tid] = v;
        sel ^= 1;
        __syncthreads();
    }
    int base = sbuf[sel][tid] - s;     // exclusive prefix over thread-chunks
    int run = base;
    #pragma unroll
    for (int i = 0; i < 4; ++i) { soff[tid * 4 + i] = run; run += c[i]; }
    __syncthreads();

    if (role >= 1) {                   // ---- scatter (no atomics) ----
        int e = (role - 1) * 256 + tid;
        int sub = pairs[2 * e];
        csr_obj[soff[sub] + rank[e]] = pairs[2 * e + 1];
        return;
    }

    // ---- role 0: batch-32 records ----
    int nb[4]; int t = 0;
    #pragma unroll
    for (int i = 0; i < 4; ++i) { nb[i] = (c[i] + 31) >> 5; t += nb[i]; }
    __syncthreads();
    sbuf[0][tid] = t;
    __syncthreads();
    sel = 0;
    for (int d = 1; d < 256; d <<= 1) {
        int v = sbuf[sel][tid];
        if (tid >= d) v += sbuf[sel][tid - d];
        sbuf[sel ^ 1][tid] = v;
        sel ^= 1;
        __syncthreads();
    }
    int bpos = sbuf[sel][tid] - t;
    int run2 = base;
    #pragma unroll
    for (int i = 0; i < 4; ++i) {
        int seg = tid * 4 + i;
        for (int k = 0; k < nb[i]; ++k) {
            int st = run2 + k * 32;
            int cnt = c[i] - k * 32; if (cnt > 32) cnt = 32;
            brec[bpos++] = (unsigned)st | ((unsigned)seg << 16) | ((unsigned)(cnt - 1) << 26);
        }
        run2 += c[i];
    }
    if (tid == 255) bcnt[0] = bpos;
}

// ================= k_seg: one 32-pair batch per block + copy =================
// grid 4096: bid%2==0 -> copy (2048); else batch slot b=bid/2 (2048 slots)
__global__ __launch_bounds__(256) void k_seg(const int* __restrict__ csr_obj,
                                             const unsigned* __restrict__ brec,
                                             const int* __restrict__ bcnt,
                                             const float* __restrict__ bb,
                                             const unsigned short* __restrict__ w1cT,
                                             const float* __restrict__ P,
                                             const float* __restrict__ Q,
                                             float* __restrict__ HS,
                                             const float4* __restrict__ csrc,
                                             float4* __restrict__ cdst) {
    int bid = blockIdx.x;
    if ((bid % 2) == 0) { copy_role(csrc, cdst, OFF_SEG, LEN_SEG, 2048, bid / 2); return; }
    int b = bid / 2;
    if (b >= bcnt[0]) return;
    unsigned rec = brec[b];
    const int start = rec & 0xFFFF;
    const int seg = (rec >> 16) & 0x3FF;
    const int n = ((rec >> 26) & 31) + 1;

    const int tid = threadIdx.x, w = tid >> 6, l = tid & 63;
    const int ln = l & 15, g4 = l >> 4, kb = g4 * 8;
    const int n0 = w * 256;
    const int nA = n < 16 ? n : 16;
    const int nB = n - 16;

    int iA = start + (ln < nA ? ln : nA - 1);
    int iB = (nB > 0) ? (start + 16 + (ln < nB ? ln : nB - 1)) : iA;
    int objA = csr_obj[iA];
    int objB = csr_obj[iB];

    const float* brA = &bb[((size_t)seg * 1024 + (size_t)objA) * 64];
    const float* brB = &bb[((size_t)seg * 1024 + (size_t)objB) * 64];
    float4 a0 = *(const float4*)&brA[kb];
    float4 a1 = *(const float4*)&brA[kb + 4];
    float4 a2 = *(const float4*)&brA[32 + kb];
    float4 a3 = *(const float4*)&brA[32 + kb + 4];
    float4 c0 = *(const float4*)&brB[kb];
    float4 c1 = *(const float4*)&brB[kb + 4];
    float4 c2 = *(const float4*)&brB[32 + kb];
    float4 c3 = *(const float4*)&brB[32 + kb + 4];
    bf16x8 A0a, A1a, A0b, A1b;
    A0a[0] = (short)f2bf(a0.x); A0a[1] = (short)f2bf(a0.y); A0a[2] = (short)f2bf(a0.z); A0a[3] = (short)f2bf(a0.w);
    A0a[4] = (short)f2bf(a1.x); A0a[5] = (short)f2bf(a1.y); A0a[6] = (short)f2bf(a1.z); A0a[7] = (short)f2bf(a1.w);
    A1a[0] = (short)f2bf(a2.x); A1a[1] = (short)f2bf(a2.y); A1a[2] = (short)f2bf(a2.z); A1a[3] = (short)f2bf(a2.w);
    A1a[4] = (short)f2bf(a3.x); A1a[5] = (short)f2bf(a3.y); A1a[6] = (short)f2bf(a3.z); A1a[7] = (short)f2bf(a3.w);
    A0b[0] = (short)f2bf(c0.x); A0b[1] = (short)f2bf(c0.y); A0b[2] = (short)f2bf(c0.z); A0b[3] = (short)f2bf(c0.w);
    A0b[4] = (short)f2bf(c1.x); A0b[5] = (short)f2bf(c1.y); A0b[6] = (short)f2bf(c1.z); A0b[7] = (short)f2bf(c1.w);
    A1b[0] = (short)f2bf(c2.x); A1b[1] = (short)f2bf(c2.y); A1b[2] = (short)f2bf(c2.z); A1b[3] = (short)f2bf(c2.w);
    A1b[4] = (short)f2bf(c3.x); A1b[5] = (short)f2bf(c3.y); A1b[6] = (short)f2bf(c3.z); A1b[7] = (short)f2bf(c3.w);

    int raA0 = __shfl(objA, g4 * 4 + 0), raA1 = __shfl(objA, g4 * 4 + 1);
    int raA2 = __shfl(objA, g4 * 4 + 2), raA3 = __shfl(objA, g4 * 4 + 3);
    int raB0 = __shfl(objB, g4 * 4 + 0), raB1 = __shfl(objB, g4 * 4 + 1);
    int raB2 = __shfl(objB, g4 * 4 + 2), raB3 = __shfl(objB, g4 * 4 + 3);
    bool vA0 = (g4 * 4 + 0) < nA, vA1 = (g4 * 4 + 1) < nA;
    bool vA2 = (g4 * 4 + 2) < nA, vA3 = (g4 * 4 + 3) < nA;
    bool vB0 = (g4 * 4 + 0) < nB, vB1 = (g4 * 4 + 1) < nB;
    bool vB2 = (g4 * 4 + 2) < nB, vB3 = (g4 * 4 + 3) < nB;

    #pragma unroll 4
    for (int f = 0; f < 16; ++f) {
        int col = n0 + f * 16 + ln;
        const unsigned short* wr = &w1cT[(size_t)col * 64];
        bf16x8 b0 = *(const bf16x8*)&wr[kb];
        bf16x8 b1 = *(const bf16x8*)&wr[32 + kb];
        f32x4 dA = {0.f, 0.f, 0.f, 0.f};
        dA = __builtin_amdgcn_mfma_f32_16x16x32_bf16(A0a, b0, dA, 0, 0, 0);
        dA = __builtin_amdgcn_mfma_f32_16x16x32_bf16(A1a, b1, dA, 0, 0, 0);
        f32x4 dB = {0.f, 0.f, 0.f, 0.f};
        dB = __builtin_amdgcn_mfma_f32_16x16x32_bf16(A0b, b0, dB, 0, 0, 0);
        dB = __builtin_amdgcn_mfma_f32_16x16x32_bf16(A1b, b1, dB, 0, 0, 0);
        float pv = P[(size_t)seg * 1024 + col];
        float qA0 = Q[(size_t)raA0 * 1024 + col];
        float qA1 = Q[(size_t)raA1 * 1024 + col];
        float qA2 = Q[(size_t)raA2 * 1024 + col];
        float qA3 = Q[(size_t)raA3 * 1024 + col];
        float qB0 = Q[(size_t)raB0 * 1024 + col];
        float qB1 = Q[(size_t)raB1 * 1024 + col];
        float qB2 = Q[(size_t)raB2 * 1024 + col];
        float qB3 = Q[(size_t)raB3 * 1024 + col];
        float h = 0.f;
        h += vA0 ? fmaxf(dA[0] + pv + qA0, 0.f) : 0.f;
        h += vA1 ? fmaxf(dA[1] + pv + qA1, 0.f) : 0.f;
        h += vA2 ? fmaxf(dA[2] + pv + qA2, 0.f) : 0.f;
        h += vA3 ? fmaxf(dA[3] + pv + qA3, 0.f) : 0.f;
        h += vB0 ? fmaxf(dB[0] + pv + qB0, 0.f) : 0.f;
        h += vB1 ? fmaxf(dB[1] + pv + qB1, 0.f) : 0.f;
        h += vB2 ? fmaxf(dB[2] + pv + qB2, 0.f) : 0.f;
        h += vB3 ? fmaxf(dB[3] + pv + qB3, 0.f) : 0.f;
        h += __shfl_xor(h, 16);
        h += __shfl_xor(h, 32);
        if (l < 16) atomicAdd(&HS[(size_t)seg * 1024 + n0 + f * 16 + l], h);
    }
}

// ================= k_out: (feats + HS@W2 + cnt*b2)/(1+cnt) + copy =================
// grid 1152: bid%9==8 -> gemm (128); else copy (1024)
__global__ __launch_bounds__(256) void k_out(const float* __restrict__ HS,
                                             const unsigned short* __restrict__ w2T,
                                             const float* __restrict__ feats,
                                             const float* __restrict__ b2,
                                             const int* __restrict__ counts,
                                             float* __restrict__ out0,
                                             const float4* __restrict__ csrc,
                                             float4* __restrict__ cdst) {
    int bid = blockIdx.x;
    if ((bid % 9) != 8) { copy_role(csrc, cdst, OFF_OUT, LEN_OUT, 1024, (bid / 9) * 8 + (bid % 9)); return; }
    int job = bid / 9;
    int m0 = (job >> 3) * 64, n0 = (job & 7) * 64;
    int tid = threadIdx.x, w = tid >> 6, l = tid & 63;
    int ln = l & 15, kb = (l >> 4) * 8;
    int row = m0 + w * 16 + ln;
    f32x4 acc[4] = {};
    for (int k0 = 0; k0 < 1024; k0 += 32) {
        const float* hp = &HS[(size_t)row * 1024 + k0 + kb];
        float4 h0 = *(const float4*)&hp[0];
        float4 h1 = *(const float4*)&hp[4];
        bf16x8 a;
        a[0] = (short)f2bf(h0.x); a[1] = (short)f2bf(h0.y); a[2] = (short)f2bf(h0.z); a[3] = (short)f2bf(h0.w);
        a[4] = (short)f2bf(h1.x); a[5] = (short)f2bf(h1.y); a[6] = (short)f2bf(h1.z); a[7] = (short)f2bf(h1.w);
        #pragma unroll
        for (int f = 0; f < 4; ++f) {
            bf16x8 b = *(const bf16x8*)&w2T[(size_t)(n0 + f * 16 + ln) * 1024 + k0 + kb];
            acc[f] = __builtin_amdgcn_mfma_f32_16x16x32_bf16(a, b, acc[f], 0, 0, 0);
        }
    }
    int mr = m0 + w * 16 + (l >> 4) * 4;
    float cv[4], inv[4];
    #pragma unroll
    for (int r = 0; r < 4; ++r) {
        float c = (float)counts[mr + r];
        cv[r] = c;
        inv[r] = 1.0f / (1.0f + c);
    }
    #pragma unroll
    for (int f = 0; f < 4; ++f) {
        int n = n0 + f * 16 + ln;
        float b2v = b2[n];
        #pragma unroll
        for (int r = 0; r < 4; ++r) {
            float fv = feats[(size_t)(mr + r) * 512 + n];
            out0[(size_t)(mr + r) * 512 + n] = (fv + acc[f][r] + cv[r] * b2v) * inv[r];
        }
    }
}

extern "C" void kernel_launch(void* const* d_in, const int* in_sizes, int n_in,
                              void* d_out, int out_size, void* d_ws, size_t ws_size,
                              hipStream_t stream) {
    const float* feats = (const float*)d_in[0];
    const float* bb    = (const float*)d_in[1];
    const int*   pairs = (const int*)d_in[2];
    const float* W1    = (const float*)d_in[3];
    const float* b1    = (const float*)d_in[4];
    const float* W2    = (const float*)d_in[5];
    const float* b2    = (const float*)d_in[6];

    float* out        = (float*)d_out;
    float* out_feats  = out;
    float* out_bb     = out + (size_t)N_OBJ * 512;
    float* out_pairs  = out + (size_t)N_OBJ * 512 + (size_t)N_OBJ * N_OBJ * 64;

    // ---- workspace layout (~13.7 MB) ----
    // [0,4MB): featsb [0,1M) + w1pqT [1M,3M) — dead after k_b; HS (f32 4MB) aliases it
    char* w = (char*)d_ws;
    unsigned short* featsb = (unsigned short*)w;
    unsigned short* w1pqT  = (unsigned short*)(w + (1u << 20));
    float*          HS     = (float*)w;
    unsigned short* w1cT   = (unsigned short*)(w + (4u << 20));
    unsigned short* w2T    = (unsigned short*)(w + (4u << 20) + (128u << 10));
    float* P = (float*)(w + (5u << 20) + (128u << 10));
    float* Q = (float*)(w + (9u << 20) + (128u << 10));
    char* ints = w + (13u << 20) + (128u << 10);
    int*      counts  = (int*)ints;                       // 4 KB
    int*      csr_obj = (int*)(ints + 4096);              // 128 KB
    unsigned* brec    = (unsigned*)(ints + 4096 + 131072);// 16 KB
    int*      bcnt    = (int*)(ints + 4096 + 131072 + 16384);
    int*      rank    = (int*)(ints + 4096 + 131072 + 16384 + 64); // 128 KB

    const float4* cbb  = (const float4*)bb;
    float4*       cobb = (float4*)out_bb;

    hipMemsetAsync(counts, 0, 4096, stream);

    k_a<<<3168, 256, 0, stream>>>(W1, W2, feats, pairs, w1pqT, w1cT, w2T, featsb,
                                  out_pairs, counts, rank, cbb, cobb);
    k_b<<<1344, 256, 0, stream>>>(counts, rank, pairs, csr_obj, brec, bcnt,
                                  featsb, w1pqT, b1, P, Q, cbb, cobb);

    hipMemsetAsync(HS, 0, (size_t)N_OBJ * 1024 * sizeof(float), stream);

    k_seg<<<4096, 256, 0, stream>>>(csr_obj, brec, bcnt, bb, w1cT, P, Q, HS, cbb, cobb);
    k_out<<<1152, 256, 0, stream>>>(HS, w2T, feats, b2, counts, out_feats, cbb, cobb);
}